// Round 4
// baseline (204.990 us; speedup 1.0000x reference)
//
#include <hip/hip_runtime.h>
#include <hip/hip_bf16.h>

// B=2, C=256 (nh=8, hd=32), H=W=64, HW=4096.
// 3x { dw3x3 + bias -> pw1x1 + bias } then softmax(QK^T/sqrt(32))V.
// pw writes Q,K transposed bf16 [bh][pos][32] (Q pre-scaled by log2e/sqrt(32)),
// V natural bf16 [b][c][pos]. Attention: 16x16x32 bf16 MFMA flash, no-max
// softmax (scores bounded ~|1|), swapped-S layout, P via LDS b64 roundtrip.

#define HW 4096
#define CDIM 256
#define SCALE_LOG2E 0.2550348543f  // (1/sqrt(32)) * log2(e)

typedef short bf16x8 __attribute__((ext_vector_type(8)));
typedef float f32x4 __attribute__((ext_vector_type(4)));

__device__ inline unsigned short f2bf(float f) {  // RNE bf16
  unsigned u = __float_as_uint(f);
  u = (u + 0x7fffu + ((u >> 16) & 1u)) >> 16;
  return (unsigned short)u;
}

__device__ inline unsigned cvtpk(float lo, float hi) {  // 2xf32 -> packed bf16
  unsigned r;
  asm("v_cvt_pk_bf16_f32 %0, %1, %2" : "=v"(r) : "v"(lo), "v"(hi));
  return r;
}

// ---------------- depthwise 3x3 + bias (fp32) ----------------
__global__ __launch_bounds__(256) void dw_kernel(
    const float* __restrict__ x, const float* __restrict__ wt,
    const float* __restrict__ bias, float* __restrict__ out) {
  int idx = blockIdx.x * 256 + threadIdx.x;
  int p = idx & (HW - 1);
  int c = (idx >> 12) & (CDIM - 1);
  int h = p >> 6, ww = p & 63;
  const float* xc = x + (size_t)(idx >> 12) * HW;
  const float* wc = wt + c * 9;
  float acc = bias[c];
#pragma unroll
  for (int kh = 0; kh < 3; ++kh) {
    int hh = h + kh - 1;
    if (hh < 0 || hh > 63) continue;
#pragma unroll
    for (int kw = 0; kw < 3; ++kw) {
      int wn = ww + kw - 1;
      if (wn < 0 || wn > 63) continue;
      acc += wc[kh * 3 + kw] * xc[hh * 64 + wn];
    }
  }
  out[idx] = acc;
}

// ---------------- pointwise 1x1 GEMM, bf16 epilogues ----------------
// MODE 1: transposed bf16 out[((b*8+h)*4096+p)*32 + d], scaled by oscale.
// MODE 3: natural bf16 out[(b*256+co)*4096 + p].
template <int MODE>
__global__ __launch_bounds__(256) void pw_kernel(
    const float* __restrict__ t, const float* __restrict__ w,
    const float* __restrict__ bias, unsigned short* __restrict__ out,
    float oscale) {
  __shared__ __align__(16) float Wt[64 * 68];
  __shared__ __align__(16) float Tt[64 * 68];
  int bid = blockIdx.x;              // 2 * 4 * 64
  int pt = bid & 63;
  int cot = (bid >> 6) & 3;
  int bb = bid >> 8;
  int p0 = pt * 64, co0 = cot * 64;
  int tid = threadIdx.x;
  int tco = tid >> 4, tp = tid & 15;
  float acc[4][4] = {};
  const float* tb = t + (size_t)bb * CDIM * HW;
  for (int k0 = 0; k0 < 256; k0 += 64) {
    __syncthreads();
#pragma unroll
    for (int i = 0; i < 16; ++i) {
      int flat = i * 256 + tid;
      int ci = flat & 63, col = flat >> 6;
      Wt[ci * 68 + col] = w[(size_t)(co0 + col) * 256 + (k0 + ci)];
      Tt[col * 68 + ci] = tb[(size_t)(k0 + col) * HW + p0 + ci];
    }
    __syncthreads();
#pragma unroll
    for (int ci = 0; ci < 64; ++ci) {
      float4 wv = *(const float4*)(Wt + ci * 68 + tco * 4);
      float4 tv = *(const float4*)(Tt + ci * 68 + tp * 4);
      float av[4] = {wv.x, wv.y, wv.z, wv.w};
      float bv[4] = {tv.x, tv.y, tv.z, tv.w};
#pragma unroll
      for (int ii = 0; ii < 4; ++ii)
#pragma unroll
        for (int jj = 0; jj < 4; ++jj) acc[ii][jj] += av[ii] * bv[jj];
    }
  }
  if (MODE == 1) {
    int coB = co0 + tco * 4;
    int hh = coB >> 5, d0 = coB & 31;  // 4-elem block never crosses a head
    float bv0 = bias[coB], bv1 = bias[coB + 1], bv2 = bias[coB + 2], bv3 = bias[coB + 3];
    size_t rowb = (size_t)(bb * 8 + hh) * HW;
#pragma unroll
    for (int jj = 0; jj < 4; ++jj) {
      int p = p0 + tp * 4 + jj;
      ushort4 pk = make_ushort4(f2bf((acc[0][jj] + bv0) * oscale),
                                f2bf((acc[1][jj] + bv1) * oscale),
                                f2bf((acc[2][jj] + bv2) * oscale),
                                f2bf((acc[3][jj] + bv3) * oscale));
      *(ushort4*)(out + (rowb + p) * 32 + d0) = pk;
    }
  } else {
#pragma unroll
    for (int ii = 0; ii < 4; ++ii) {
      int co = co0 + tco * 4 + ii;
      float bv = bias[co];
      ushort4 pk = make_ushort4(f2bf(acc[ii][0] + bv), f2bf(acc[ii][1] + bv),
                                f2bf(acc[ii][2] + bv), f2bf(acc[ii][3] + bv));
      *(ushort4*)(out + (size_t)(bb * CDIM + co) * HW + p0 + tp * 4) = pk;
    }
  }
}

// ---------------- MFMA flash attention ----------------
// grid: 16 bh * 32 qblocks = 512 blocks, 256 thr (4 waves). Wave: 2 q-tiles
// (32 q). K chunk = 64 positions, double-buffered LDS.
// LDS map (bytes): K bufs @0,@5120 (64 rows * 80B); V bufs @10240,@14848
// (32 rows * 144B); P^T @19456 + wave*2304 (16 rows * 144B).
__device__ inline void process_qtile(
    bf16x8 qf, bf16x8 kf0, bf16x8 kf1, bf16x8 kf2, bf16x8 kf3,
    bf16x8 vf00, bf16x8 vf01, bf16x8 vf10, bf16x8 vf11,
    unsigned char* Pw, int lq, int lg, f32x4& Oa, f32x4& Ob, float& ps) {
  f32x4 zz = {0.f, 0.f, 0.f, 0.f};
  // S^T tiles: T[kpos][q] = sum_d K[kpos][d] * Qs[q][d]  (Qs pre-scaled)
  f32x4 t0 = __builtin_amdgcn_mfma_f32_16x16x32_bf16(kf0, qf, zz, 0, 0, 0);
  f32x4 t1 = __builtin_amdgcn_mfma_f32_16x16x32_bf16(kf1, qf, zz, 0, 0, 0);
  f32x4 t2 = __builtin_amdgcn_mfma_f32_16x16x32_bf16(kf2, qf, zz, 0, 0, 0);
  f32x4 t3 = __builtin_amdgcn_mfma_f32_16x16x32_bf16(kf3, qf, zz, 0, 0, 0);
  float p[16];
#pragma unroll
  for (int r = 0; r < 4; ++r) {
    p[r] = exp2f(t0[r]);
    p[4 + r] = exp2f(t1[r]);
    p[8 + r] = exp2f(t2[r]);
    p[12 + r] = exp2f(t3[r]);
  }
  float s = 0.f;
#pragma unroll
  for (int i = 0; i < 16; ++i) s += p[i];
  ps += s;
  // pack consecutive-kpos pairs, write P^T[q][kpos] (wave-private region;
  // same-wave DS ordering makes write->read safe; fences stop TBAA reordering)
  uint2 w0 = {cvtpk(p[0], p[1]), cvtpk(p[2], p[3])};
  uint2 w1 = {cvtpk(p[4], p[5]), cvtpk(p[6], p[7])};
  uint2 w2 = {cvtpk(p[8], p[9]), cvtpk(p[10], p[11])};
  uint2 w3 = {cvtpk(p[12], p[13]), cvtpk(p[14], p[15])};
  unsigned char* Pr = Pw + lq * 144 + lg * 8;
  asm volatile("" ::: "memory");  // keep these stores after prior call's loads
  *(uint2*)(Pr + 0) = w0;    // kpos kt*16 + 4*lg, kt=0
  *(uint2*)(Pr + 32) = w1;
  *(uint2*)(Pr + 64) = w2;
  *(uint2*)(Pr + 96) = w3;
  asm volatile("" ::: "memory");  // uint2 stores vs short-vec loads: no TBAA reorder
  bf16x8 pa0 = *(const bf16x8*)(Pw + lq * 144 + lg * 16);        // kk 0..31
  bf16x8 pa1 = *(const bf16x8*)(Pw + lq * 144 + 64 + lg * 16);   // kk 32..63
  Oa = __builtin_amdgcn_mfma_f32_16x16x32_bf16(pa0, vf00, Oa, 0, 0, 0);
  Oa = __builtin_amdgcn_mfma_f32_16x16x32_bf16(pa1, vf10, Oa, 0, 0, 0);
  Ob = __builtin_amdgcn_mfma_f32_16x16x32_bf16(pa0, vf01, Ob, 0, 0, 0);
  Ob = __builtin_amdgcn_mfma_f32_16x16x32_bf16(pa1, vf11, Ob, 0, 0, 0);
}

__global__ __launch_bounds__(256) void attn_kernel(
    const unsigned short* __restrict__ Qt, const unsigned short* __restrict__ Kt,
    const unsigned short* __restrict__ Vn, float* __restrict__ out) {
  __shared__ __align__(16) unsigned char lds[28672];
  int bid = blockIdx.x;
  int qb = bid & 31, bh = bid >> 5;
  int b = bh >> 3, n = bh & 7;
  int tid = threadIdx.x;
  int l = tid & 63, wv = tid >> 6;
  int lq = l & 15, lg = l >> 4;

  const unsigned short* Qg = Qt + (size_t)bh * HW * 32;
  const unsigned short* Kg = Kt + (size_t)bh * HW * 32;
  const unsigned short* Vg = Vn + (size_t)(b * CDIM + n * 32) * HW;

  int q0w = qb * 128 + wv * 32;
  bf16x8 qf0 = *(const bf16x8*)(Qg + (size_t)(q0w + lq) * 32 + lg * 8);
  bf16x8 qf1 = *(const bf16x8*)(Qg + (size_t)(q0w + 16 + lq) * 32 + lg * 8);

  f32x4 O00 = {0.f, 0.f, 0.f, 0.f}, O01 = O00, O10 = O00, O11 = O00;
  float ps0 = 0.f, ps1 = 0.f;

  // staging: K chunk = 4KB contiguous (256 x uint4); V chunk = 32 rows x 128B
  const uint4* Ksrc4 = (const uint4*)Kg;
  int krow = tid >> 2, kcol = tid & 3;
  int vrow = tid >> 3, vcol = tid & 7;
  const unsigned short* Vrowp = Vg + (size_t)vrow * HW + vcol * 8;

  uint4 kst = Ksrc4[tid];
  uint4 vst = *(const uint4*)Vrowp;
  *(uint4*)(lds + krow * 80 + kcol * 16) = kst;
  *(uint4*)(lds + 10240 + vrow * 144 + vcol * 16) = vst;
  int cur = 0;

#pragma unroll 1
  for (int c = 0; c < 64; ++c) {
    if (c < 63) {  // issue next-chunk global loads early (latency under compute)
      kst = Ksrc4[(c + 1) * 256 + tid];
      vst = *(const uint4*)(Vrowp + (c + 1) * 64);
    }
    __syncthreads();  // lds[cur] ready
    {
      const unsigned char* Kb = lds + (cur ? 5120 : 0);
      const unsigned char* Vb = lds + 10240 + (cur ? 4608 : 0);
      bf16x8 kf0 = *(const bf16x8*)(Kb + (0 * 16 + lq) * 80 + lg * 16);
      bf16x8 kf1 = *(const bf16x8*)(Kb + (1 * 16 + lq) * 80 + lg * 16);
      bf16x8 kf2 = *(const bf16x8*)(Kb + (2 * 16 + lq) * 80 + lg * 16);
      bf16x8 kf3 = *(const bf16x8*)(Kb + (3 * 16 + lq) * 80 + lg * 16);
      bf16x8 vf00 = *(const bf16x8*)(Vb + lq * 144 + lg * 16);          // kk0-31, d0-15
      bf16x8 vf01 = *(const bf16x8*)(Vb + (lq + 16) * 144 + lg * 16);   // kk0-31, d16-31
      bf16x8 vf10 = *(const bf16x8*)(Vb + lq * 144 + 64 + lg * 16);     // kk32-63
      bf16x8 vf11 = *(const bf16x8*)(Vb + (lq + 16) * 144 + 64 + lg * 16);
      unsigned char* Pw = lds + 19456 + wv * 2304;
      process_qtile(qf0, kf0, kf1, kf2, kf3, vf00, vf01, vf10, vf11, Pw, lq, lg, O00, O01, ps0);
      process_qtile(qf1, kf0, kf1, kf2, kf3, vf00, vf01, vf10, vf11, Pw, lq, lg, O10, O11, ps1);
    }
    __syncthreads();  // all reads of lds[cur] done
    if (c < 63) {
      unsigned char* Kd = lds + (cur ? 0 : 5120);
      unsigned char* Vd = lds + 10240 + (cur ? 0 : 4608);
      *(uint4*)(Kd + krow * 80 + kcol * 16) = kst;
      *(uint4*)(Vd + vrow * 144 + vcol * 16) = vst;
    }
    cur ^= 1;
  }

  // row sums: lane holds partial for q = lq over its kpos groups -> reduce over g
  ps0 += __shfl_xor(ps0, 16);
  ps0 += __shfl_xor(ps0, 32);
  ps1 += __shfl_xor(ps1, 16);
  ps1 += __shfl_xor(ps1, 32);
  // O rows are q_local = 4*lg + r; fetch that row's sum from lane (4*lg+r)
  float ri0[4], ri1[4];
#pragma unroll
  for (int r = 0; r < 4; ++r) {
    int src = (4 * lg + r) * 4;
    ri0[r] = 1.0f / __int_as_float(__builtin_amdgcn_ds_bpermute(src, __float_as_int(ps0)));
    ri1[r] = 1.0f / __int_as_float(__builtin_amdgcn_ds_bpermute(src, __float_as_int(ps1)));
  }
  size_t ob = (size_t)(b * CDIM + n * 32) * HW;
#pragma unroll
  for (int r = 0; r < 4; ++r) {
    int qp0 = q0w + 4 * lg + r;
    out[ob + (size_t)lq * HW + qp0]        = O00[r] * ri0[r];
    out[ob + (size_t)(lq + 16) * HW + qp0] = O01[r] * ri0[r];
    out[ob + (size_t)lq * HW + qp0 + 16]        = O10[r] * ri1[r];
    out[ob + (size_t)(lq + 16) * HW + qp0 + 16] = O11[r] * ri1[r];
  }
}

extern "C" void kernel_launch(void* const* d_in, const int* in_sizes, int n_in,
                              void* d_out, int out_size, void* d_ws, size_t ws_size,
                              hipStream_t stream) {
  const float* x   = (const float*)d_in[0];
  const float* ctx = (const float*)d_in[1];
  const float* q_dw  = (const float*)d_in[2];
  const float* q_dwb = (const float*)d_in[3];
  const float* q_pw  = (const float*)d_in[4];
  const float* q_pwb = (const float*)d_in[5];
  const float* k_dw  = (const float*)d_in[6];
  const float* k_dwb = (const float*)d_in[7];
  const float* k_pw  = (const float*)d_in[8];
  const float* k_pwb = (const float*)d_in[9];
  const float* v_dw  = (const float*)d_in[10];
  const float* v_dwb = (const float*)d_in[11];
  const float* v_pw  = (const float*)d_in[12];
  const float* v_pwb = (const float*)d_in[13];

  const size_t N = (size_t)2 * CDIM * HW;   // elems per tensor
  float* t = (float*)d_out;                 // dw temp reuses output buffer
  unsigned short* Qc = (unsigned short*)d_ws;              // 4MB
  unsigned short* Kc = Qc + N;                             // 4MB
  unsigned short* Vc = Kc + N;                             // 4MB

  const int dwGrid = (int)(N / 256);
  dw_kernel<<<dwGrid, 256, 0, stream>>>(x, q_dw, q_dwb, t);
  pw_kernel<1><<<512, 256, 0, stream>>>(t, q_pw, q_pwb, Qc, SCALE_LOG2E);
  dw_kernel<<<dwGrid, 256, 0, stream>>>(ctx, k_dw, k_dwb, t);
  pw_kernel<1><<<512, 256, 0, stream>>>(t, k_pw, k_pwb, Kc, 1.0f);
  dw_kernel<<<dwGrid, 256, 0, stream>>>(ctx, v_dw, v_dwb, t);
  pw_kernel<3><<<512, 256, 0, stream>>>(t, v_pw, v_pwb, Vc, 1.0f);

  attn_kernel<<<512, 256, 0, stream>>>(Qc, Kc, Vc, (float*)d_out);
}

// Round 5
// 138.199 us; speedup vs baseline: 1.4833x; 1.4833x over previous
//
#include <hip/hip_runtime.h>
#include <hip/hip_bf16.h>

// B=2, C=256 (nh=8, hd=32), H=W=64, HW=4096.
// dw3x3(fp32->bf16) -> pw1x1 bf16 MFMA -> flash attn bf16 MFMA (no-max softmax).
// Q,K transposed bf16 [bh][pos][32] (Q pre-scaled log2e/sqrt(32)); V bf16 [c][p].

#define HW 4096
#define CDIM 256
#define SCALE_LOG2E 0.2550348543f  // (1/sqrt(32)) * log2(e)

typedef short bf16x8 __attribute__((ext_vector_type(8)));
typedef float f32x4 __attribute__((ext_vector_type(4)));

__device__ inline unsigned short f2bf(float f) {  // RNE bf16
  unsigned u = __float_as_uint(f);
  u = (u + 0x7fffu + ((u >> 16) & 1u)) >> 16;
  return (unsigned short)u;
}

__device__ inline unsigned cvtpk(float lo, float hi) {  // 2xf32 -> packed bf16
  unsigned r;
  asm("v_cvt_pk_bf16_f32 %0, %1, %2" : "=v"(r) : "v"(lo), "v"(hi));
  return r;
}

__device__ inline float fexp2(float x) {  // raw v_exp_f32 (inputs far from denorm)
#if __has_builtin(__builtin_amdgcn_exp2f)
  return __builtin_amdgcn_exp2f(x);
#else
  return exp2f(x);
#endif
}

// ---------------- depthwise 3x3 + bias: fp32 in, bf16 out ----------------
__global__ __launch_bounds__(256) void dw_kernel(
    const float* __restrict__ x, const float* __restrict__ wt,
    const float* __restrict__ bias, unsigned short* __restrict__ out) {
  int idx = blockIdx.x * 256 + threadIdx.x;
  int p = idx & (HW - 1);
  int c = (idx >> 12) & (CDIM - 1);
  int h = p >> 6, ww = p & 63;
  const float* xc = x + (size_t)(idx >> 12) * HW;
  const float* wc = wt + c * 9;
  float acc = bias[c];
#pragma unroll
  for (int kh = 0; kh < 3; ++kh) {
    int hh = h + kh - 1;
    if (hh < 0 || hh > 63) continue;
#pragma unroll
    for (int kw = 0; kw < 3; ++kw) {
      int wn = ww + kw - 1;
      if (wn < 0 || wn > 63) continue;
      acc += wc[kh * 3 + kw] * xc[hh * 64 + wn];
    }
  }
  out[idx] = f2bf(acc);
}

// ---------------- pointwise 1x1: bf16 MFMA GEMM ----------------
// out[co][p] = sum_ci W[co][ci] * T[ci][p].  Block: 64co x 64p, 4 waves
// (wave = 16 co x 64 p). B-tile transposed into LDS [p][256ci] pitch 512B
// with XOR swizzle s(p)=((p^(p>>3))&7)<<4 (write & read conflict-free).
// MODE 1: out transposed bf16 [bh][pos][32], scaled. MODE 3: natural [c][p].
template <int MODE>
__global__ __launch_bounds__(256) void pw_mfma(
    const unsigned short* __restrict__ t, const float* __restrict__ w,
    const float* __restrict__ bias, unsigned short* __restrict__ out,
    float oscale) {
  __shared__ __align__(16) unsigned char Bs[64 * 512];
  int bid = blockIdx.x;  // 2 * 4 * 64
  int pt = bid & 63, cot = (bid >> 6) & 3, bb = bid >> 8;
  int p0 = pt * 64, co0 = cot * 64;
  int tid = threadIdx.x;
  int wv = tid >> 6, l = tid & 63, lq = l & 15, lg = l >> 4;

  // A fragments: 16 co rows of W (fp32 -> bf16), all 8 k-steps, reg-resident
  bf16x8 af[8];
  {
    const float* wr = w + (size_t)(co0 + wv * 16 + lq) * 256;
#pragma unroll
    for (int kt = 0; kt < 8; ++kt) {
      float4 a = *(const float4*)(wr + kt * 32 + lg * 8);
      float4 bq = *(const float4*)(wr + kt * 32 + lg * 8 + 4);
      union { unsigned u[4]; bf16x8 v; } cv;
      cv.u[0] = cvtpk(a.x, a.y);  cv.u[1] = cvtpk(a.z, a.w);
      cv.u[2] = cvtpk(bq.x, bq.y); cv.u[3] = cvtpk(bq.z, bq.w);
      af[kt] = cv.v;
    }
  }
  // stage B: thread gathers 8ci x 8p block, transposes in-reg, 8x b128 writes
  {
    int cb = tid >> 3, po = tid & 7;  // ci-block (8 ci), p-octet
    const unsigned short* src = t + (size_t)bb * (CDIM * HW) + (size_t)(cb * 8) * HW + p0 + po * 8;
    uint4 r[8];
#pragma unroll
    for (int i = 0; i < 8; ++i) r[i] = *(const uint4*)(src + (size_t)i * HW);
#pragma unroll
    for (int jj = 0; jj < 8; ++jj) {
      uint4 o;
#pragma unroll
      for (int ww = 0; ww < 4; ++ww) {
        unsigned a = ((const unsigned*)&r[2 * ww])[jj >> 1];
        unsigned b = ((const unsigned*)&r[2 * ww + 1])[jj >> 1];
        unsigned lo = (jj & 1) ? (a >> 16) : (a & 0xffffu);
        unsigned hi = (jj & 1) ? (b & 0xffff0000u) : (b << 16);
        (&o.x)[ww] = lo | hi;
      }
      int p = po * 8 + jj;
      int swz = ((p ^ (p >> 3)) & 7) << 4;
      *(uint4*)(Bs + p * 512 + ((cb * 16) ^ swz)) = o;
    }
  }
  __syncthreads();
  f32x4 acc[4] = {};
#pragma unroll
  for (int nt = 0; nt < 4; ++nt) {
    int p = nt * 16 + lq;
    int swz = ((p ^ (p >> 3)) & 7) << 4;
    const unsigned char* Bp = Bs + p * 512;
#pragma unroll
    for (int kt = 0; kt < 8; ++kt) {
      bf16x8 bf = *(const bf16x8*)(Bp + ((kt * 64 + lg * 16) ^ swz));
      acc[nt] = __builtin_amdgcn_mfma_f32_16x16x32_bf16(af[kt], bf, acc[nt], 0, 0, 0);
    }
  }
  // D: col(lane&15)=p, row(lg*4+r)=co  [HW-validated mapping]
  if (MODE == 1) {
    int co = co0 + wv * 16 + lg * 4;
    int d0 = co & 31;
    float b0 = bias[co], b1 = bias[co + 1], b2 = bias[co + 2], b3 = bias[co + 3];
    size_t rowb = (size_t)(bb * 8 + (co >> 5)) * HW;
#pragma unroll
    for (int nt = 0; nt < 4; ++nt) {
      int p = p0 + nt * 16 + lq;
      ushort4 pk = make_ushort4(f2bf((acc[nt][0] + b0) * oscale),
                                f2bf((acc[nt][1] + b1) * oscale),
                                f2bf((acc[nt][2] + b2) * oscale),
                                f2bf((acc[nt][3] + b3) * oscale));
      *(ushort4*)(out + (rowb + p) * 32 + d0) = pk;
    }
  } else {
    int cob = co0 + wv * 16 + lg * 4;
#pragma unroll
    for (int r = 0; r < 4; ++r) {
      float bv = bias[cob + r];
      size_t rb = (size_t)bb * (CDIM * HW) + (size_t)(cob + r) * HW + p0;
#pragma unroll
      for (int nt = 0; nt < 4; ++nt)
        out[rb + nt * 16 + lq] = f2bf(acc[nt][r] + bv);
    }
  }
}

// ---------------- MFMA flash attention ----------------
// grid: 16 bh * 64 qblocks = 1024 blocks, 256 thr (4 waves), 1 q-tile/wave
// (16 q) -> 4096 waves = 4/SIMD. K chunk = 64 pos, double-buffered LDS.
// LDS: K bufs @0,@5120 (64r*80B); V bufs @10240,@14848 (32r*144B);
// P^T @19456 + wave*2304 (16r*144B).
__device__ inline void process_qtile(
    bf16x8 qf, bf16x8 kf0, bf16x8 kf1, bf16x8 kf2, bf16x8 kf3,
    bf16x8 vf00, bf16x8 vf01, bf16x8 vf10, bf16x8 vf11,
    unsigned char* Pw, int lq, int lg, f32x4& Oa, f32x4& Ob, float& ps) {
  f32x4 zz = {0.f, 0.f, 0.f, 0.f};
  f32x4 t0 = __builtin_amdgcn_mfma_f32_16x16x32_bf16(kf0, qf, zz, 0, 0, 0);
  f32x4 t1 = __builtin_amdgcn_mfma_f32_16x16x32_bf16(kf1, qf, zz, 0, 0, 0);
  f32x4 t2 = __builtin_amdgcn_mfma_f32_16x16x32_bf16(kf2, qf, zz, 0, 0, 0);
  f32x4 t3 = __builtin_amdgcn_mfma_f32_16x16x32_bf16(kf3, qf, zz, 0, 0, 0);
  float p[16];
#pragma unroll
  for (int r = 0; r < 4; ++r) {
    p[r] = fexp2(t0[r]);
    p[4 + r] = fexp2(t1[r]);
    p[8 + r] = fexp2(t2[r]);
    p[12 + r] = fexp2(t3[r]);
  }
  float s01 = (p[0] + p[1]) + (p[2] + p[3]);
  float s23 = (p[4] + p[5]) + (p[6] + p[7]);
  float s45 = (p[8] + p[9]) + (p[10] + p[11]);
  float s67 = (p[12] + p[13]) + (p[14] + p[15]);
  ps += (s01 + s23) + (s45 + s67);
  uint2 w0 = {cvtpk(p[0], p[1]), cvtpk(p[2], p[3])};
  uint2 w1 = {cvtpk(p[4], p[5]), cvtpk(p[6], p[7])};
  uint2 w2 = {cvtpk(p[8], p[9]), cvtpk(p[10], p[11])};
  uint2 w3 = {cvtpk(p[12], p[13]), cvtpk(p[14], p[15])};
  unsigned char* Pr = Pw + lq * 144 + lg * 8;
  asm volatile("" ::: "memory");
  *(uint2*)(Pr + 0) = w0;
  *(uint2*)(Pr + 32) = w1;
  *(uint2*)(Pr + 64) = w2;
  *(uint2*)(Pr + 96) = w3;
  asm volatile("" ::: "memory");
  bf16x8 pa0 = *(const bf16x8*)(Pw + lq * 144 + lg * 16);       // kk 0..31
  bf16x8 pa1 = *(const bf16x8*)(Pw + lq * 144 + 64 + lg * 16);  // kk 32..63
  Oa = __builtin_amdgcn_mfma_f32_16x16x32_bf16(pa0, vf00, Oa, 0, 0, 0);
  Oa = __builtin_amdgcn_mfma_f32_16x16x32_bf16(pa1, vf10, Oa, 0, 0, 0);
  Ob = __builtin_amdgcn_mfma_f32_16x16x32_bf16(pa0, vf01, Ob, 0, 0, 0);
  Ob = __builtin_amdgcn_mfma_f32_16x16x32_bf16(pa1, vf11, Ob, 0, 0, 0);
}

__global__ __launch_bounds__(256, 4) void attn_kernel(
    const unsigned short* __restrict__ Qt, const unsigned short* __restrict__ Kt,
    const unsigned short* __restrict__ Vn, float* __restrict__ out) {
  __shared__ __align__(16) unsigned char lds[28672];
  int bid = blockIdx.x;
  int qb = bid & 63, bh = bid >> 6;
  int b = bh >> 3, n = bh & 7;
  int tid = threadIdx.x;
  int l = tid & 63, wv = tid >> 6;
  int lq = l & 15, lg = l >> 4;

  const unsigned short* Qg = Qt + (size_t)bh * HW * 32;
  const unsigned short* Kg = Kt + (size_t)bh * HW * 32;
  const unsigned short* Vg = Vn + (size_t)(b * CDIM + n * 32) * HW;

  int q0w = qb * 64 + wv * 16;
  bf16x8 qf = *(const bf16x8*)(Qg + (size_t)(q0w + lq) * 32 + lg * 8);

  f32x4 Oa = {0.f, 0.f, 0.f, 0.f}, Ob = Oa;
  float ps = 0.f;

  const uint4* Ksrc4 = (const uint4*)Kg;
  int krow = tid >> 2, kcol = tid & 3;
  int vrow = tid >> 3, vcol = tid & 7;
  const unsigned short* Vrowp = Vg + (size_t)vrow * HW + vcol * 8;

  uint4 kst = Ksrc4[tid];
  uint4 vst = *(const uint4*)Vrowp;
  *(uint4*)(lds + krow * 80 + kcol * 16) = kst;
  *(uint4*)(lds + 10240 + vrow * 144 + vcol * 16) = vst;
  int cur = 0;

#pragma unroll 1
  for (int c = 0; c < 64; ++c) {
    if (c < 63) {
      kst = Ksrc4[(c + 1) * 256 + tid];
      vst = *(const uint4*)(Vrowp + (c + 1) * 64);
    }
    __syncthreads();
    {
      const unsigned char* Kb = lds + (cur ? 5120 : 0);
      const unsigned char* Vb = lds + 10240 + (cur ? 4608 : 0);
      bf16x8 kf0 = *(const bf16x8*)(Kb + (0 * 16 + lq) * 80 + lg * 16);
      bf16x8 kf1 = *(const bf16x8*)(Kb + (1 * 16 + lq) * 80 + lg * 16);
      bf16x8 kf2 = *(const bf16x8*)(Kb + (2 * 16 + lq) * 80 + lg * 16);
      bf16x8 kf3 = *(const bf16x8*)(Kb + (3 * 16 + lq) * 80 + lg * 16);
      bf16x8 vf00 = *(const bf16x8*)(Vb + lq * 144 + lg * 16);
      bf16x8 vf01 = *(const bf16x8*)(Vb + (lq + 16) * 144 + lg * 16);
      bf16x8 vf10 = *(const bf16x8*)(Vb + lq * 144 + 64 + lg * 16);
      bf16x8 vf11 = *(const bf16x8*)(Vb + (lq + 16) * 144 + 64 + lg * 16);
      unsigned char* Pw = lds + 19456 + wv * 2304;
      process_qtile(qf, kf0, kf1, kf2, kf3, vf00, vf01, vf10, vf11, Pw, lq, lg, Oa, Ob, ps);
    }
    __syncthreads();
    if (c < 63) {
      unsigned char* Kd = lds + (cur ? 0 : 5120);
      unsigned char* Vd = lds + 10240 + (cur ? 0 : 4608);
      *(uint4*)(Kd + krow * 80 + kcol * 16) = kst;
      *(uint4*)(Vd + vrow * 144 + vcol * 16) = vst;
    }
    cur ^= 1;
  }

  ps += __shfl_xor(ps, 16);
  ps += __shfl_xor(ps, 32);
  float ri[4];
#pragma unroll
  for (int r = 0; r < 4; ++r) {
    int src = (4 * lg + r) * 4;
    ri[r] = 1.0f / __int_as_float(__builtin_amdgcn_ds_bpermute(src, __float_as_int(ps)));
  }
  size_t ob = (size_t)(b * CDIM + n * 32) * HW;
#pragma unroll
  for (int r = 0; r < 4; ++r) {
    int qp = q0w + 4 * lg + r;
    out[ob + (size_t)lq * HW + qp]        = Oa[r] * ri[r];
    out[ob + (size_t)(lq + 16) * HW + qp] = Ob[r] * ri[r];
  }
}

extern "C" void kernel_launch(void* const* d_in, const int* in_sizes, int n_in,
                              void* d_out, int out_size, void* d_ws, size_t ws_size,
                              hipStream_t stream) {
  const float* x   = (const float*)d_in[0];
  const float* ctx = (const float*)d_in[1];
  const float* q_dw  = (const float*)d_in[2];
  const float* q_dwb = (const float*)d_in[3];
  const float* q_pw  = (const float*)d_in[4];
  const float* q_pwb = (const float*)d_in[5];
  const float* k_dw  = (const float*)d_in[6];
  const float* k_dwb = (const float*)d_in[7];
  const float* k_pw  = (const float*)d_in[8];
  const float* k_pwb = (const float*)d_in[9];
  const float* v_dw  = (const float*)d_in[10];
  const float* v_dwb = (const float*)d_in[11];
  const float* v_pw  = (const float*)d_in[12];
  const float* v_pwb = (const float*)d_in[13];

  const size_t N = (size_t)2 * CDIM * HW;
  unsigned short* t = (unsigned short*)d_out;     // bf16 dw temp (4MB of 8MB)
  unsigned short* Qc = (unsigned short*)d_ws;     // 4MB each
  unsigned short* Kc = Qc + N;
  unsigned short* Vc = Kc + N;

  const int dwGrid = (int)(N / 256);  // 8192
  dw_kernel<<<dwGrid, 256, 0, stream>>>(x, q_dw, q_dwb, t);
  pw_mfma<1><<<512, 256, 0, stream>>>(t, q_pw, q_pwb, Qc, SCALE_LOG2E);
  dw_kernel<<<dwGrid, 256, 0, stream>>>(ctx, k_dw, k_dwb, t);
  pw_mfma<1><<<512, 256, 0, stream>>>(t, k_pw, k_pwb, Kc, 1.0f);
  dw_kernel<<<dwGrid, 256, 0, stream>>>(ctx, v_dw, v_dwb, t);
  pw_mfma<3><<<512, 256, 0, stream>>>(t, v_pw, v_pwb, Vc, 1.0f);

  attn_kernel<<<1024, 256, 0, stream>>>(Qc, Kc, Vc, (float*)d_out);
}

// Round 6
// 91.459 us; speedup vs baseline: 2.2413x; 1.5111x over previous
//
#include <hip/hip_runtime.h>
#include <hip/hip_bf16.h>

// B=2, C=256 (nh=8, hd=32), H=W=64, HW=4096.
// dw3x3(fp32->bf16, fused 3 tensors) -> pw1x1 bf16 MFMA (fused 3) ->
// flash attn bf16 MFMA 32x32x16, no-max softmax, permlane P-redistribute,
// 8-wave blocks with in-block K-split (partials merge via LDS; exact since no-max).

#define HW 4096
#define CDIM 256
#define SCALE_LOG2E 0.2550348543f  // (1/sqrt(32)) * log2(e)

typedef short bf16x8 __attribute__((ext_vector_type(8)));
typedef float f32x4 __attribute__((ext_vector_type(4)));
typedef float f32x16 __attribute__((ext_vector_type(16)));

__device__ inline unsigned short f2bf(float f) {  // RNE bf16
  unsigned u = __float_as_uint(f);
  u = (u + 0x7fffu + ((u >> 16) & 1u)) >> 16;
  return (unsigned short)u;
}

__device__ inline unsigned cvtpk(float lo, float hi) {  // 2xf32 -> packed bf16
  unsigned r;
  asm("v_cvt_pk_bf16_f32 %0, %1, %2" : "=v"(r) : "v"(lo), "v"(hi));
  return r;
}

__device__ inline float fexp2(float x) {
#if __has_builtin(__builtin_amdgcn_exp2f)
  return __builtin_amdgcn_exp2f(x);
#else
  return exp2f(x);
#endif
}

// permlane32_swap: a' = [a.lo, b.lo], b' = [a.hi, b.hi]  (row1 of a <-> row0 of b)
__device__ inline void plswap(unsigned& a, unsigned& b) {
#if __has_builtin(__builtin_amdgcn_permlane32_swap)
  auto r = __builtin_amdgcn_permlane32_swap((int)a, (int)b, false, false);
  a = (unsigned)r[0];
  b = (unsigned)r[1];
#else
  unsigned as = __shfl_xor((int)a, 32), bs = __shfl_xor((int)b, 32);
  bool hi = (threadIdx.x & 32) != 0;
  unsigned na = hi ? bs : a;   // [a.lo, b.lo]
  unsigned nb = hi ? b : as;   // [a.hi, b.hi]
  a = na; b = nb;
#endif
}

// ---------------- depthwise 3x3 + bias (all 3 tensors, float4 rows) ----------------
__global__ __launch_bounds__(256) void dw_all(
    const float* __restrict__ x, const float* __restrict__ ctx,
    const float* __restrict__ qdw, const float* __restrict__ qdwb,
    const float* __restrict__ kdw, const float* __restrict__ kdwb,
    const float* __restrict__ vdw, const float* __restrict__ vdwb,
    unsigned short* __restrict__ tq, unsigned short* __restrict__ tk,
    unsigned short* __restrict__ tv) {
  int gid = blockIdx.x * 256 + threadIdx.x;  // quad id; 3 * 2*256*1024
  int tt = gid >> 19;
  int r = gid & 524287;
  int q4 = r & 1023;          // quad within plane
  int plane = r >> 10;        // b*256 + c
  int c = plane & 255;
  int w0 = (q4 & 15) * 4, h = q4 >> 4;
  const float* src = (tt == 0 ? x : ctx) + (size_t)plane * HW;
  const float* wc = (tt == 0 ? qdw : (tt == 1 ? kdw : vdw)) + c * 9;
  float bv = (tt == 0 ? qdwb : (tt == 1 ? kdwb : vdwb))[c];
  float acc0 = bv, acc1 = bv, acc2 = bv, acc3 = bv;
#pragma unroll
  for (int kh = 0; kh < 3; ++kh) {
    int hh = h + kh - 1;
    if (hh < 0 || hh > 63) continue;
    const float* row = src + hh * 64 + w0;
    float4 m = *(const float4*)row;
    float lft = (w0 > 0) ? row[-1] : 0.f;
    float rgt = (w0 < 60) ? row[4] : 0.f;
    float e0 = lft, e1 = m.x, e2 = m.y, e3 = m.z, e4 = m.w, e5 = rgt;
    float w_0 = wc[kh * 3 + 0], w_1 = wc[kh * 3 + 1], w_2 = wc[kh * 3 + 2];
    acc0 += w_0 * e0 + w_1 * e1 + w_2 * e2;
    acc1 += w_0 * e1 + w_1 * e2 + w_2 * e3;
    acc2 += w_0 * e2 + w_1 * e3 + w_2 * e4;
    acc3 += w_0 * e3 + w_1 * e4 + w_2 * e5;
  }
  unsigned short* out = (tt == 0 ? tq : (tt == 1 ? tk : tv));
  ushort4 pk = make_ushort4(f2bf(acc0), f2bf(acc1), f2bf(acc2), f2bf(acc3));
  *(ushort4*)(out + (size_t)plane * HW + h * 64 + w0) = pk;
}

// ---------------- pointwise 1x1 bf16 MFMA (all 3 tensors) ----------------
// tt<2: transposed bf16 out[((b*8+h)*4096+p)*32+d] (tt==0 scaled); tt==2: natural.
__global__ __launch_bounds__(256) void pw_all(
    const unsigned short* __restrict__ tq, const unsigned short* __restrict__ tk,
    const unsigned short* __restrict__ tv,
    const float* __restrict__ qw, const float* __restrict__ qbs,
    const float* __restrict__ kw, const float* __restrict__ kbs,
    const float* __restrict__ vw, const float* __restrict__ vbs,
    unsigned short* __restrict__ Qc, unsigned short* __restrict__ Kc,
    unsigned short* __restrict__ Vc) {
  __shared__ __align__(16) unsigned char Bs[64 * 512];
  int tt = blockIdx.x >> 9;
  int bid = blockIdx.x & 511;
  const unsigned short* t = tt == 0 ? tq : (tt == 1 ? tk : tv);
  const float* w = tt == 0 ? qw : (tt == 1 ? kw : vw);
  const float* bias = tt == 0 ? qbs : (tt == 1 ? kbs : vbs);
  unsigned short* out = tt == 0 ? Qc : (tt == 1 ? Kc : Vc);
  float oscale = tt == 0 ? SCALE_LOG2E : 1.0f;

  int pt = bid & 63, cot = (bid >> 6) & 3, bb = bid >> 8;
  int p0 = pt * 64, co0 = cot * 64;
  int tid = threadIdx.x;
  int wv = tid >> 6, l = tid & 63, lq = l & 15, lg = l >> 4;

  bf16x8 af[8];
  {
    const float* wr = w + (size_t)(co0 + wv * 16 + lq) * 256;
#pragma unroll
    for (int kt = 0; kt < 8; ++kt) {
      float4 a = *(const float4*)(wr + kt * 32 + lg * 8);
      float4 bq = *(const float4*)(wr + kt * 32 + lg * 8 + 4);
      union { unsigned u[4]; bf16x8 v; } cv;
      cv.u[0] = cvtpk(a.x, a.y);  cv.u[1] = cvtpk(a.z, a.w);
      cv.u[2] = cvtpk(bq.x, bq.y); cv.u[3] = cvtpk(bq.z, bq.w);
      af[kt] = cv.v;
    }
  }
  {
    int cb = tid >> 3, po = tid & 7;
    const unsigned short* src = t + (size_t)bb * (CDIM * HW) + (size_t)(cb * 8) * HW + p0 + po * 8;
    uint4 r[8];
#pragma unroll
    for (int i = 0; i < 8; ++i) r[i] = *(const uint4*)(src + (size_t)i * HW);
#pragma unroll
    for (int jj = 0; jj < 8; ++jj) {
      uint4 o;
#pragma unroll
      for (int ww = 0; ww < 4; ++ww) {
        unsigned a = ((const unsigned*)&r[2 * ww])[jj >> 1];
        unsigned b = ((const unsigned*)&r[2 * ww + 1])[jj >> 1];
        unsigned lo = (jj & 1) ? (a >> 16) : (a & 0xffffu);
        unsigned hi = (jj & 1) ? (b & 0xffff0000u) : (b << 16);
        (&o.x)[ww] = lo | hi;
      }
      int p = po * 8 + jj;
      int swz = ((p ^ (p >> 3)) & 7) << 4;
      *(uint4*)(Bs + p * 512 + ((cb * 16) ^ swz)) = o;
    }
  }
  __syncthreads();
  f32x4 acc[4] = {};
#pragma unroll
  for (int nt = 0; nt < 4; ++nt) {
    int p = nt * 16 + lq;
    int swz = ((p ^ (p >> 3)) & 7) << 4;
    const unsigned char* Bp = Bs + p * 512;
#pragma unroll
    for (int kt = 0; kt < 8; ++kt) {
      bf16x8 bf = *(const bf16x8*)(Bp + ((kt * 64 + lg * 16) ^ swz));
      acc[nt] = __builtin_amdgcn_mfma_f32_16x16x32_bf16(af[kt], bf, acc[nt], 0, 0, 0);
    }
  }
  if (tt < 2) {
    int co = co0 + wv * 16 + lg * 4;
    int d0 = co & 31;
    float b0 = bias[co], b1 = bias[co + 1], b2 = bias[co + 2], b3 = bias[co + 3];
    size_t rowb = (size_t)(bb * 8 + (co >> 5)) * HW;
#pragma unroll
    for (int nt = 0; nt < 4; ++nt) {
      int p = p0 + nt * 16 + lq;
      ushort4 pk = make_ushort4(f2bf((acc[nt][0] + b0) * oscale),
                                f2bf((acc[nt][1] + b1) * oscale),
                                f2bf((acc[nt][2] + b2) * oscale),
                                f2bf((acc[nt][3] + b3) * oscale));
      *(ushort4*)(out + (rowb + p) * 32 + d0) = pk;
    }
  } else {
    int cob = co0 + wv * 16 + lg * 4;
#pragma unroll
    for (int r = 0; r < 4; ++r) {
      float bv = bias[cob + r];
      size_t rb = (size_t)bb * (CDIM * HW) + (size_t)(cob + r) * HW + p0;
#pragma unroll
      for (int nt = 0; nt < 4; ++nt)
        out[rb + nt * 16 + lq] = f2bf(acc[nt][r] + bv);
    }
  }
}

// ---------------- MFMA flash attention, 32x32 tiles, 8 waves, K-split ----------------
// grid 512 (16 bh x 32 qb), 512 thr. Wave wv: qg=wv&3 (32 q), ks=wv>>2 (kpos half).
// chunk = 64 kpos, 32 chunks/wave, single barrier per chunk, dbuf LDS.
// LDS: K[ks][buf][64r x 80B] @0..20480; V[ks][buf][32r x 144B] @20480..38912.
// End: ksplit partials merged via LDS overlay (exact: no-max softmax => add).
__global__ __launch_bounds__(512, 4) void attn_kernel(
    const unsigned short* __restrict__ Qt, const unsigned short* __restrict__ Kt,
    const unsigned short* __restrict__ Vn, float* __restrict__ out) {
  __shared__ __align__(16) unsigned char lds[38912];
  int bid0 = blockIdx.x;
  int bid = (bid0 & 7) * 64 + (bid0 >> 3);  // XCD-chunked swizzle (512 % 8 == 0)
  int qb = bid & 31, bh = bid >> 5;
  int b = bh >> 3, n = bh & 7;
  int tid = threadIdx.x;
  int l = tid & 63, wv = tid >> 6;
  int qg = wv & 3, ks = wv >> 2;
  int lq = l & 31, hi = l >> 5;

  const unsigned short* Qg = Qt + (size_t)bh * (HW * 32);
  const unsigned short* Kg = Kt + (size_t)bh * (HW * 32);
  const unsigned short* Vg = Vn + (size_t)(b * CDIM + n * 32) * HW;

  int q0 = qb * 128 + qg * 32;
  bf16x8 qfh0 = *(const bf16x8*)(Qg + (size_t)(q0 + lq) * 32 + hi * 8);
  bf16x8 qfh1 = *(const bf16x8*)(Qg + (size_t)(q0 + lq) * 32 + 16 + hi * 8);

  f32x16 O = {};  // O[q(reg)][d=lq]
  float ps = 0.f;

  int ht = tid & 255;  // half-block stages its own ksplit
  int krow = ht >> 2, kcol = ht & 3;
  int vrow = ht >> 3, vcol = ht & 7;
  unsigned char* Kb0 = lds + (ks * 2 + 0) * 5120;
  unsigned char* Kb1 = lds + (ks * 2 + 1) * 5120;
  unsigned char* Vb0 = lds + 20480 + (ks * 2 + 0) * 4608;
  unsigned char* Vb1 = lds + 20480 + (ks * 2 + 1) * 4608;
  const uint4* Ksrc = (const uint4*)(Kg + (size_t)(ks * 2048) * 32);
  const unsigned short* Vsrc = Vg + (size_t)vrow * HW + ks * 2048 + vcol * 8;

  // prologue: chunk0 -> LDS buf0; chunk1 -> regs
  uint4 kst = Ksrc[krow * 4 + kcol];
  uint4 vst = *(const uint4*)Vsrc;
  *(uint4*)(Kb0 + krow * 80 + kcol * 16) = kst;
  *(uint4*)(Vb0 + vrow * 144 + vcol * 16) = vst;
  kst = Ksrc[(64 + krow) * 4 + kcol];
  vst = *(const uint4*)(Vsrc + 64);

#pragma unroll 1
  for (int c = 0; c < 32; ++c) {
    __syncthreads();  // buf[c&1] writes visible; prev reads of buf[(c+1)&1] done
    unsigned char* Kcur = (c & 1) ? Kb1 : Kb0;
    unsigned char* Vcur = (c & 1) ? Vb1 : Vb0;
    if (c < 31) {
      unsigned char* Kn = (c & 1) ? Kb0 : Kb1;
      unsigned char* Vw = (c & 1) ? Vb0 : Vb1;
      *(uint4*)(Kn + krow * 80 + kcol * 16) = kst;
      *(uint4*)(Vw + vrow * 144 + vcol * 16) = vst;
      if (c < 30) {
        kst = Ksrc[((c + 2) * 64 + krow) * 4 + kcol];
        vst = *(const uint4*)(Vsrc + (c + 2) * 64);
      }
    }
#pragma unroll
    for (int t2 = 0; t2 < 2; ++t2) {  // S^T tile: rows kpos(t2*32..), cols q
      const unsigned char* Krow = Kcur + (t2 * 32 + lq) * 80 + hi * 16;
      bf16x8 kfa = *(const bf16x8*)(Krow);
      bf16x8 kfb = *(const bf16x8*)(Krow + 32);
      f32x16 zz = {};
      __builtin_amdgcn_s_setprio(1);
      f32x16 st = __builtin_amdgcn_mfma_f32_32x32x16_bf16(kfa, qfh0, zz, 0, 0, 0);
      st = __builtin_amdgcn_mfma_f32_32x32x16_bf16(kfb, qfh1, st, 0, 0, 0);
      __builtin_amdgcn_s_setprio(0);
      float p[16];
#pragma unroll
      for (int r = 0; r < 16; ++r) p[r] = fexp2(st[r]);
      float s0 = (p[0] + p[1]) + (p[2] + p[3]);
      float s1 = (p[4] + p[5]) + (p[6] + p[7]);
      float s2 = (p[8] + p[9]) + (p[10] + p[11]);
      float s3 = (p[12] + p[13]) + (p[14] + p[15]);
      ps += (s0 + s1) + (s2 + s3);
      // u[2rr+h] = kpos 8rr+4hi+2h+{0,1} (lane-local); redistribute to PV A-frags
      unsigned u0 = cvtpk(p[0], p[1]),  u1 = cvtpk(p[2], p[3]);
      unsigned u2 = cvtpk(p[4], p[5]),  u3 = cvtpk(p[6], p[7]);
      unsigned u4 = cvtpk(p[8], p[9]),  u5 = cvtpk(p[10], p[11]);
      unsigned u6 = cvtpk(p[12], p[13]), u7 = cvtpk(p[14], p[15]);
      plswap(u0, u2);  // u0 = A0.w0, u2 = A0.w2
      plswap(u1, u3);  // u1 = A0.w1, u3 = A0.w3
      plswap(u4, u6);  // u4 = A1.w0, u6 = A1.w2
      plswap(u5, u7);
      union { unsigned w[4]; bf16x8 v; } A0, A1;
      A0.w[0] = u0; A0.w[1] = u1; A0.w[2] = u2; A0.w[3] = u3;
      A1.w[0] = u4; A1.w[1] = u5; A1.w[2] = u6; A1.w[3] = u7;
      const unsigned char* Vrow = Vcur + lq * 144 + t2 * 64;
      bf16x8 vf0 = *(const bf16x8*)(Vrow + hi * 16);
      bf16x8 vf1 = *(const bf16x8*)(Vrow + 32 + hi * 16);
      __builtin_amdgcn_s_setprio(1);
      O = __builtin_amdgcn_mfma_f32_32x32x16_bf16(A0.v, vf0, O, 0, 0, 0);
      O = __builtin_amdgcn_mfma_f32_32x32x16_bf16(A1.v, vf1, O, 0, 0, 0);
      __builtin_amdgcn_s_setprio(0);
    }
  }

  ps += __shfl_xor(ps, 32);  // lane now holds sum for q = lq (this ksplit)
  __syncthreads();           // all K/V LDS use done; overlay exchange buffers
  float* Ox = (float*)lds;                    // [4 qg][32 d][33]
  float* SumX = (float*)(lds + 16896);        // [4 qg][32 q]
  if (ks == 1) {
    float* Or = Ox + qg * (32 * 33) + lq * 33;
#pragma unroll
    for (int rr = 0; rr < 4; ++rr) {
      float4 vv = {O[rr * 4 + 0], O[rr * 4 + 1], O[rr * 4 + 2], O[rr * 4 + 3]};
      *(float4*)(Or + 8 * rr + 4 * hi) = vv;
    }
    if (hi == 0) SumX[qg * 32 + lq] = ps;
  }
  __syncthreads();
  if (ks == 0) {
    const float* Or = Ox + qg * (32 * 33) + lq * 33;
    float rtot = ps + SumX[qg * 32 + lq];
    float rv = 1.0f / rtot;  // lane holds 1/sum for q = lq
    size_t ob = ((size_t)(b * CDIM) + n * 32 + lq) * HW;  // channel row (d = lq)
#pragma unroll
    for (int rr = 0; rr < 4; ++rr) {
      int qlb = 8 * rr + 4 * hi;
      float4 part = *(const float4*)(Or + qlb);
      float4 res;
#pragma unroll
      for (int j = 0; j < 4; ++j) {
        float sq = __int_as_float(
            __builtin_amdgcn_ds_bpermute((qlb + j) * 4, __float_as_int(rv)));
        (&res.x)[j] = (O[rr * 4 + j] + (&part.x)[j]) * sq;
      }
      *(float4*)(out + ob + q0 + qlb) = res;
    }
  }
}

extern "C" void kernel_launch(void* const* d_in, const int* in_sizes, int n_in,
                              void* d_out, int out_size, void* d_ws, size_t ws_size,
                              hipStream_t stream) {
  const float* x   = (const float*)d_in[0];
  const float* ctx = (const float*)d_in[1];
  const float* q_dw  = (const float*)d_in[2];
  const float* q_dwb = (const float*)d_in[3];
  const float* q_pw  = (const float*)d_in[4];
  const float* q_pwb = (const float*)d_in[5];
  const float* k_dw  = (const float*)d_in[6];
  const float* k_dwb = (const float*)d_in[7];
  const float* k_pw  = (const float*)d_in[8];
  const float* k_pwb = (const float*)d_in[9];
  const float* v_dw  = (const float*)d_in[10];
  const float* v_dwb = (const float*)d_in[11];
  const float* v_pw  = (const float*)d_in[12];
  const float* v_pwb = (const float*)d_in[13];

  const size_t N = (size_t)2 * CDIM * HW;         // elems per tensor
  unsigned short* Qc = (unsigned short*)d_ws;      // ws: Qc,Kc,Vc,tv (16MB)
  unsigned short* Kc = Qc + N;
  unsigned short* Vc = Kc + N;
  unsigned short* tv = Vc + N;
  unsigned short* tq = (unsigned short*)d_out;     // d_out hosts tq+tk (8MB)
  unsigned short* tk = tq + N;

  dw_all<<<6144, 256, 0, stream>>>(x, ctx, q_dw, q_dwb, k_dw, k_dwb, v_dw, v_dwb,
                                   tq, tk, tv);
  pw_all<<<1536, 256, 0, stream>>>(tq, tk, tv, q_pw, q_pwb, k_pw, k_pwb,
                                   v_pw, v_pwb, Qc, Kc, Vc);
  attn_kernel<<<512, 512, 0, stream>>>(Qc, Kc, Vc, (float*)d_out);
}

// Round 7
// 85.615 us; speedup vs baseline: 2.3943x; 1.0683x over previous
//
#include <hip/hip_runtime.h>
#include <hip/hip_bf16.h>

// B=2, C=256 (nh=8, hd=32), H=W=64, HW=4096.
// dw3x3(fp32->bf16) -> pw1x1 bf16 MFMA -> flash attn bf16 MFMA 32x32x16,
// no-max softmax (exact: scores tiny), permlane P-redistribute, 8-wave blocks
// with in-block K-split; partials merged via LDS (exact since no-max).

#define HW 4096
#define CDIM 256
#define SCALE_LOG2E 0.2550348543f  // (1/sqrt(32)) * log2(e)

typedef short bf16x8 __attribute__((ext_vector_type(8)));
typedef float f32x2 __attribute__((ext_vector_type(2)));
typedef float f32x4 __attribute__((ext_vector_type(4)));
typedef float f32x16 __attribute__((ext_vector_type(16)));

__device__ inline unsigned short f2bf(float f) {  // RNE bf16
  unsigned u = __float_as_uint(f);
  u = (u + 0x7fffu + ((u >> 16) & 1u)) >> 16;
  return (unsigned short)u;
}

__device__ inline unsigned cvtpk(float lo, float hi) {  // 2xf32 -> packed bf16
  unsigned r;
  asm("v_cvt_pk_bf16_f32 %0, %1, %2" : "=v"(r) : "v"(lo), "v"(hi));
  return r;
}

__device__ inline float fexp2(float x) {
#if __has_builtin(__builtin_amdgcn_exp2f)
  return __builtin_amdgcn_exp2f(x);
#else
  return exp2f(x);
#endif
}

// permlane32_swap: a' = [a.lo, b.lo], b' = [a.hi, b.hi]
__device__ inline void plswap(unsigned& a, unsigned& b) {
#if __has_builtin(__builtin_amdgcn_permlane32_swap)
  auto r = __builtin_amdgcn_permlane32_swap((int)a, (int)b, false, false);
  a = (unsigned)r[0];
  b = (unsigned)r[1];
#else
  unsigned as = __shfl_xor((int)a, 32), bs = __shfl_xor((int)b, 32);
  bool hi = (threadIdx.x & 32) != 0;
  unsigned na = hi ? bs : a;
  unsigned nb = hi ? b : as;
  a = na; b = nb;
#endif
}

// ---------------- depthwise 3x3 + bias; pass0: x->tq, pass1: ctx->{tk,tv} ----------------
__global__ __launch_bounds__(256) void dw_all(
    const float* __restrict__ x, const float* __restrict__ ctx,
    const float* __restrict__ qdw, const float* __restrict__ qdwb,
    const float* __restrict__ kdw, const float* __restrict__ kdwb,
    const float* __restrict__ vdw, const float* __restrict__ vdwb,
    unsigned short* __restrict__ tq, unsigned short* __restrict__ tk,
    unsigned short* __restrict__ tv) {
  int gid = blockIdx.x * 256 + threadIdx.x;  // 2 * 524288 quads
  int pass = gid >> 19;                      // uniform per block
  int r = gid & 524287;
  int q4 = r & 1023;
  int plane = r >> 10;   // b*256 + c
  int c = plane & 255;
  int w0 = (q4 & 15) * 4, h = q4 >> 4;
  const float* src = (pass ? ctx : x) + (size_t)plane * HW;

  float e[3][6];
#pragma unroll
  for (int kh = 0; kh < 3; ++kh) {
    int hh = h + kh - 1;
    if (hh < 0 || hh > 63) {
#pragma unroll
      for (int j = 0; j < 6; ++j) e[kh][j] = 0.f;
    } else {
      const float* row = src + hh * 64 + w0;
      float4 m = *(const float4*)row;
      e[kh][0] = (w0 > 0) ? row[-1] : 0.f;
      e[kh][1] = m.x; e[kh][2] = m.y; e[kh][3] = m.z; e[kh][4] = m.w;
      e[kh][5] = (w0 < 60) ? row[4] : 0.f;
    }
  }
  size_t obase = (size_t)plane * HW + h * 64 + w0;
  if (pass == 0) {
    const float* wc = qdw + c * 9;
    float bv = qdwb[c];
    float a0 = bv, a1 = bv, a2 = bv, a3 = bv;
#pragma unroll
    for (int kh = 0; kh < 3; ++kh) {
      float w_0 = wc[kh * 3], w_1 = wc[kh * 3 + 1], w_2 = wc[kh * 3 + 2];
      a0 += w_0 * e[kh][0] + w_1 * e[kh][1] + w_2 * e[kh][2];
      a1 += w_0 * e[kh][1] + w_1 * e[kh][2] + w_2 * e[kh][3];
      a2 += w_0 * e[kh][2] + w_1 * e[kh][3] + w_2 * e[kh][4];
      a3 += w_0 * e[kh][3] + w_1 * e[kh][4] + w_2 * e[kh][5];
    }
    *(ushort4*)(tq + obase) = make_ushort4(f2bf(a0), f2bf(a1), f2bf(a2), f2bf(a3));
  } else {
    const float* wk = kdw + c * 9;
    const float* wvv = vdw + c * 9;
    float bk = kdwb[c], bv2 = vdwb[c];
    float k0 = bk, k1 = bk, k2 = bk, k3 = bk;
    float v0 = bv2, v1 = bv2, v2 = bv2, v3 = bv2;
#pragma unroll
    for (int kh = 0; kh < 3; ++kh) {
      float kw0 = wk[kh * 3], kw1 = wk[kh * 3 + 1], kw2 = wk[kh * 3 + 2];
      float vw0 = wvv[kh * 3], vw1 = wvv[kh * 3 + 1], vw2 = wvv[kh * 3 + 2];
      k0 += kw0 * e[kh][0] + kw1 * e[kh][1] + kw2 * e[kh][2];
      k1 += kw0 * e[kh][1] + kw1 * e[kh][2] + kw2 * e[kh][3];
      k2 += kw0 * e[kh][2] + kw1 * e[kh][3] + kw2 * e[kh][4];
      k3 += kw0 * e[kh][3] + kw1 * e[kh][4] + kw2 * e[kh][5];
      v0 += vw0 * e[kh][0] + vw1 * e[kh][1] + vw2 * e[kh][2];
      v1 += vw0 * e[kh][1] + vw1 * e[kh][2] + vw2 * e[kh][3];
      v2 += vw0 * e[kh][2] + vw1 * e[kh][3] + vw2 * e[kh][4];
      v3 += vw0 * e[kh][3] + vw1 * e[kh][4] + vw2 * e[kh][5];
    }
    *(ushort4*)(tk + obase) = make_ushort4(f2bf(k0), f2bf(k1), f2bf(k2), f2bf(k3));
    *(ushort4*)(tv + obase) = make_ushort4(f2bf(v0), f2bf(v1), f2bf(v2), f2bf(v3));
  }
}

// ---------------- pointwise 1x1 bf16 MFMA (all 3 tensors) ----------------
__global__ __launch_bounds__(256) void pw_all(
    const unsigned short* __restrict__ tq, const unsigned short* __restrict__ tk,
    const unsigned short* __restrict__ tv,
    const float* __restrict__ qw, const float* __restrict__ qbs,
    const float* __restrict__ kw, const float* __restrict__ kbs,
    const float* __restrict__ vw, const float* __restrict__ vbs,
    unsigned short* __restrict__ Qc, unsigned short* __restrict__ Kc,
    unsigned short* __restrict__ Vc) {
  __shared__ __align__(16) unsigned char Bs[64 * 512];
  int tt = blockIdx.x >> 9;
  int bid = blockIdx.x & 511;
  const unsigned short* t = tt == 0 ? tq : (tt == 1 ? tk : tv);
  const float* w = tt == 0 ? qw : (tt == 1 ? kw : vw);
  const float* bias = tt == 0 ? qbs : (tt == 1 ? kbs : vbs);
  unsigned short* out = tt == 0 ? Qc : (tt == 1 ? Kc : Vc);
  float oscale = tt == 0 ? SCALE_LOG2E : 1.0f;

  int pt = bid & 63, cot = (bid >> 6) & 3, bb = bid >> 8;
  int p0 = pt * 64, co0 = cot * 64;
  int tid = threadIdx.x;
  int wv = tid >> 6, l = tid & 63, lq = l & 15, lg = l >> 4;

  bf16x8 af[8];
  {
    const float* wr = w + (size_t)(co0 + wv * 16 + lq) * 256;
#pragma unroll
    for (int kt = 0; kt < 8; ++kt) {
      float4 a = *(const float4*)(wr + kt * 32 + lg * 8);
      float4 bq = *(const float4*)(wr + kt * 32 + lg * 8 + 4);
      union { unsigned u[4]; bf16x8 v; } cv;
      cv.u[0] = cvtpk(a.x, a.y);  cv.u[1] = cvtpk(a.z, a.w);
      cv.u[2] = cvtpk(bq.x, bq.y); cv.u[3] = cvtpk(bq.z, bq.w);
      af[kt] = cv.v;
    }
  }
  {
    int cb = tid >> 3, po = tid & 7;
    const unsigned short* src = t + (size_t)bb * (CDIM * HW) + (size_t)(cb * 8) * HW + p0 + po * 8;
    uint4 r[8];
#pragma unroll
    for (int i = 0; i < 8; ++i) r[i] = *(const uint4*)(src + (size_t)i * HW);
#pragma unroll
    for (int jj = 0; jj < 8; ++jj) {
      uint4 o;
#pragma unroll
      for (int ww = 0; ww < 4; ++ww) {
        unsigned a = ((const unsigned*)&r[2 * ww])[jj >> 1];
        unsigned b = ((const unsigned*)&r[2 * ww + 1])[jj >> 1];
        unsigned lo = (jj & 1) ? (a >> 16) : (a & 0xffffu);
        unsigned hi = (jj & 1) ? (b & 0xffff0000u) : (b << 16);
        (&o.x)[ww] = lo | hi;
      }
      int p = po * 8 + jj;
      int swz = ((p ^ (p >> 3)) & 7) << 4;
      *(uint4*)(Bs + p * 512 + ((cb * 16) ^ swz)) = o;
    }
  }
  __syncthreads();
  f32x4 acc[4] = {};
#pragma unroll
  for (int nt = 0; nt < 4; ++nt) {
    int p = nt * 16 + lq;
    int swz = ((p ^ (p >> 3)) & 7) << 4;
    const unsigned char* Bp = Bs + p * 512;
#pragma unroll
    for (int kt = 0; kt < 8; ++kt) {
      bf16x8 bf = *(const bf16x8*)(Bp + ((kt * 64 + lg * 16) ^ swz));
      acc[nt] = __builtin_amdgcn_mfma_f32_16x16x32_bf16(af[kt], bf, acc[nt], 0, 0, 0);
    }
  }
  if (tt < 2) {
    int co = co0 + wv * 16 + lg * 4;
    int d0 = co & 31;
    float b0 = bias[co], b1 = bias[co + 1], b2 = bias[co + 2], b3 = bias[co + 3];
    size_t rowb = (size_t)(bb * 8 + (co >> 5)) * HW;
#pragma unroll
    for (int nt = 0; nt < 4; ++nt) {
      int p = p0 + nt * 16 + lq;
      ushort4 pk = make_ushort4(f2bf((acc[nt][0] + b0) * oscale),
                                f2bf((acc[nt][1] + b1) * oscale),
                                f2bf((acc[nt][2] + b2) * oscale),
                                f2bf((acc[nt][3] + b3) * oscale));
      *(ushort4*)(out + (rowb + p) * 32 + d0) = pk;
    }
  } else {
    int cob = co0 + wv * 16 + lg * 4;
#pragma unroll
    for (int r = 0; r < 4; ++r) {
      float bv = bias[cob + r];
      size_t rb = (size_t)bb * (CDIM * HW) + (size_t)(cob + r) * HW + p0;
#pragma unroll
      for (int nt = 0; nt < 4; ++nt)
        out[rb + nt * 16 + lq] = f2bf(acc[nt][r] + bv);
    }
  }
}

// ---------------- MFMA flash attention, 32x32 tiles, 8 waves, K-split ----------------
struct AttnState {
  bf16x8 qfh0, qfh1;
  f32x16 OA, OB, ZZ;
  float ps;
  int lq, hi;
};

__device__ inline void attn_compute(AttnState& S, const unsigned char* Kcur,
                                    const unsigned char* Vcur) {
#pragma unroll
  for (int t2 = 0; t2 < 2; ++t2) {
    const unsigned char* Krow = Kcur + (t2 * 32 + S.lq) * 80 + S.hi * 16;
    bf16x8 kfa = *(const bf16x8*)(Krow);
    bf16x8 kfb = *(const bf16x8*)(Krow + 32);
    __builtin_amdgcn_s_setprio(1);
    f32x16 st = __builtin_amdgcn_mfma_f32_32x32x16_bf16(kfa, S.qfh0, S.ZZ, 0, 0, 0);
    st = __builtin_amdgcn_mfma_f32_32x32x16_bf16(kfb, S.qfh1, st, 0, 0, 0);
    __builtin_amdgcn_s_setprio(0);
    float p[16];
#pragma unroll
    for (int r = 0; r < 16; ++r) p[r] = fexp2(st[r]);
    // packed pairwise sum tree (v_pk_add_f32)
    f32x2 a0 = {p[0], p[1]},  a1 = {p[2], p[3]};
    f32x2 a2 = {p[4], p[5]},  a3 = {p[6], p[7]};
    f32x2 a4 = {p[8], p[9]},  a5 = {p[10], p[11]};
    f32x2 a6 = {p[12], p[13]}, a7 = {p[14], p[15]};
    f32x2 b0 = a0 + a1, b1 = a2 + a3, b2 = a4 + a5, b3 = a6 + a7;
    f32x2 c0 = b0 + b1, c1 = b2 + b3;
    f32x2 d0 = c0 + c1;
    S.ps += d0[0] + d0[1];
    unsigned u0 = cvtpk(p[0], p[1]),  u1 = cvtpk(p[2], p[3]);
    unsigned u2 = cvtpk(p[4], p[5]),  u3 = cvtpk(p[6], p[7]);
    unsigned u4 = cvtpk(p[8], p[9]),  u5 = cvtpk(p[10], p[11]);
    unsigned u6 = cvtpk(p[12], p[13]), u7 = cvtpk(p[14], p[15]);
    plswap(u0, u2);
    plswap(u1, u3);
    plswap(u4, u6);
    plswap(u5, u7);
    union { unsigned w[4]; bf16x8 v; } A0, A1;
    A0.w[0] = u0; A0.w[1] = u1; A0.w[2] = u2; A0.w[3] = u3;
    A1.w[0] = u4; A1.w[1] = u5; A1.w[2] = u6; A1.w[3] = u7;
    const unsigned char* Vrow = Vcur + S.lq * 144 + t2 * 64;
    bf16x8 vf0 = *(const bf16x8*)(Vrow + S.hi * 16);
    bf16x8 vf1 = *(const bf16x8*)(Vrow + 32 + S.hi * 16);
    __builtin_amdgcn_s_setprio(1);
    S.OA = __builtin_amdgcn_mfma_f32_32x32x16_bf16(A0.v, vf0, S.OA, 0, 0, 0);
    S.OB = __builtin_amdgcn_mfma_f32_32x32x16_bf16(A1.v, vf1, S.OB, 0, 0, 0);
    __builtin_amdgcn_s_setprio(0);
  }
}

__global__ __launch_bounds__(512, 4) void attn_kernel(
    const unsigned short* __restrict__ Qt, const unsigned short* __restrict__ Kt,
    const unsigned short* __restrict__ Vn, float* __restrict__ out) {
  __shared__ __align__(16) unsigned char lds[38912];
  int bid0 = blockIdx.x;
  int bid = (bid0 & 7) * 64 + (bid0 >> 3);  // XCD-chunked swizzle (512 % 8 == 0)
  int qb = bid & 31, bh = bid >> 5;
  int b = bh >> 3, n = bh & 7;
  int tid = threadIdx.x;
  int l = tid & 63, wv = tid >> 6;
  int qg = wv & 3, ks = wv >> 2;

  AttnState S;
  S.lq = l & 31; S.hi = l >> 5;
  S.OA = (f32x16){}; S.OB = (f32x16){}; S.ZZ = (f32x16){};
  S.ps = 0.f;

  const unsigned short* Qg = Qt + (size_t)bh * (HW * 32);
  const unsigned short* Kg = Kt + (size_t)bh * (HW * 32);
  const unsigned short* Vg = Vn + (size_t)(b * CDIM + n * 32) * HW;

  int q0 = qb * 128 + qg * 32;
  S.qfh0 = *(const bf16x8*)(Qg + (size_t)(q0 + S.lq) * 32 + S.hi * 8);
  S.qfh1 = *(const bf16x8*)(Qg + (size_t)(q0 + S.lq) * 32 + 16 + S.hi * 8);

  int ht = tid & 255;  // half-block stages its own ksplit
  int krow = ht >> 2, kcol = ht & 3;
  int vrow = ht >> 3, vcol = ht & 7;
  unsigned char* Kb0 = lds + (ks * 2 + 0) * 5120;
  unsigned char* Kb1 = lds + (ks * 2 + 1) * 5120;
  unsigned char* Vb0 = lds + 20480 + (ks * 2 + 0) * 4608;
  unsigned char* Vb1 = lds + 20480 + (ks * 2 + 1) * 4608;
  unsigned char* Kw0 = Kb0 + krow * 80 + kcol * 16;
  unsigned char* Kw1 = Kb1 + krow * 80 + kcol * 16;
  unsigned char* Vw0 = Vb0 + vrow * 144 + vcol * 16;
  unsigned char* Vw1 = Vb1 + vrow * 144 + vcol * 16;
  const uint4* Ksrc = (const uint4*)(Kg + (size_t)(ks * 2048) * 32);
  const unsigned short* Vsrc = Vg + (size_t)vrow * HW + ks * 2048 + vcol * 8;

  // prologue: chunk0 -> LDS buf0; chunk1 -> regs
  uint4 kst = Ksrc[krow * 4 + kcol];
  uint4 vst = *(const uint4*)Vsrc;
  *(uint4*)Kw0 = kst;
  *(uint4*)Vw0 = vst;
  kst = Ksrc[(64 + krow) * 4 + kcol];
  vst = *(const uint4*)(Vsrc + 64);

#pragma unroll 1
  for (int c = 0; c < 32; c += 2) {
    // phase A: compute chunk c (buf0); stage c+1 -> buf1; prefetch c+2
    __syncthreads();
    *(uint4*)Kw1 = kst;
    *(uint4*)Vw1 = vst;
    if (c < 30) {
      kst = Ksrc[((c + 2) * 64 + krow) * 4 + kcol];
      vst = *(const uint4*)(Vsrc + (c + 2) * 64);
    }
    attn_compute(S, Kb0, Vb0);
    // phase B: compute chunk c+1 (buf1); stage c+2 -> buf0; prefetch c+3
    __syncthreads();
    if (c < 30) {
      *(uint4*)Kw0 = kst;
      *(uint4*)Vw0 = vst;
      kst = Ksrc[((c + 3) * 64 + krow) * 4 + kcol];
      vst = *(const uint4*)(Vsrc + (c + 3) * 64);
    }
    attn_compute(S, Kb1, Vb1);
  }

  f32x16 O = S.OA + S.OB;
  float ps = S.ps;
  int lq = S.lq, hi = S.hi;
  ps += __shfl_xor(ps, 32);  // lane holds sum for q = lq (this ksplit)
  __syncthreads();           // all K/V LDS use done; overlay exchange buffers
  float* Ox = (float*)lds;                    // [4 qg][32 d][33]
  float* SumX = (float*)(lds + 16896);        // [4 qg][32 q]
  if (ks == 1) {
    float* Or = Ox + qg * (32 * 33) + lq * 33;
#pragma unroll
    for (int rr = 0; rr < 4; ++rr) {
      float4 vv = {O[rr * 4 + 0], O[rr * 4 + 1], O[rr * 4 + 2], O[rr * 4 + 3]};
      *(float4*)(Or + 8 * rr + 4 * hi) = vv;
    }
    if (hi == 0) SumX[qg * 32 + lq] = ps;
  }
  __syncthreads();
  if (ks == 0) {
    const float* Or = Ox + qg * (32 * 33) + lq * 33;
    float rtot = ps + SumX[qg * 32 + lq];
    float rv = 1.0f / rtot;  // lane holds 1/sum for q = lq
    size_t ob = ((size_t)(b * CDIM) + n * 32 + lq) * HW;  // channel row (d = lq)
#pragma unroll
    for (int rr = 0; rr < 4; ++rr) {
      int qlb = 8 * rr + 4 * hi;
      float4 part = *(const float4*)(Or + qlb);
      float4 res;
#pragma unroll
      for (int j = 0; j < 4; ++j) {
        float sq = __int_as_float(
            __builtin_amdgcn_ds_bpermute((qlb + j) * 4, __float_as_int(rv)));
        (&res.x)[j] = (O[rr * 4 + j] + (&part.x)[j]) * sq;
      }
      *(float4*)(out + ob + q0 + qlb) = res;
    }
  }
}

extern "C" void kernel_launch(void* const* d_in, const int* in_sizes, int n_in,
                              void* d_out, int out_size, void* d_ws, size_t ws_size,
                              hipStream_t stream) {
  const float* x   = (const float*)d_in[0];
  const float* ctx = (const float*)d_in[1];
  const float* q_dw  = (const float*)d_in[2];
  const float* q_dwb = (const float*)d_in[3];
  const float* q_pw  = (const float*)d_in[4];
  const float* q_pwb = (const float*)d_in[5];
  const float* k_dw  = (const float*)d_in[6];
  const float* k_dwb = (const float*)d_in[7];
  const float* k_pw  = (const float*)d_in[8];
  const float* k_pwb = (const float*)d_in[9];
  const float* v_dw  = (const float*)d_in[10];
  const float* v_dwb = (const float*)d_in[11];
  const float* v_pw  = (const float*)d_in[12];
  const float* v_pwb = (const float*)d_in[13];

  const size_t N = (size_t)2 * CDIM * HW;          // elems per tensor
  unsigned short* Qc = (unsigned short*)d_ws;       // ws: Qc,Kc,Vc,tv (16MB)
  unsigned short* Kc = Qc + N;
  unsigned short* Vc = Kc + N;
  unsigned short* tv = Vc + N;
  unsigned short* tq = (unsigned short*)d_out;      // d_out hosts tq+tk (8MB)
  unsigned short* tk = tq + N;

  dw_all<<<4096, 256, 0, stream>>>(x, ctx, q_dw, q_dwb, k_dw, k_dwb, v_dw, v_dwb,
                                   tq, tk, tv);
  pw_all<<<1536, 256, 0, stream>>>(tq, tk, tv, q_pw, q_pwb, k_pw, k_pwb,
                                   v_pw, v_pwb, Qc, Kc, Vc);
  attn_kernel<<<512, 512, 0, stream>>>(Qc, Kc, Vc, (float*)d_out);
}